// Round 1
// baseline (392.399 us; speedup 1.0000x reference)
//
#include <hip/hip_runtime.h>

#define NN 50000
#define EE 800000
#define HH 128

typedef float f32x4 __attribute__((ext_vector_type(4)));
typedef short bf16x8 __attribute__((ext_vector_type(8)));

__device__ __forceinline__ unsigned short f2bf(float f) {
  unsigned int u = __float_as_uint(f);
  u += 0x7fffu + ((u >> 16) & 1u);
  return (unsigned short)(u >> 16);
}

__device__ __forceinline__ void async_copy16(const void* g, void* l) {
  __builtin_amdgcn_global_load_lds(
      (const __attribute__((address_space(1))) unsigned int*)g,
      (__attribute__((address_space(3))) unsigned int*)l, 16, 0, 0);
}

// ---------------- graph preprocessing ----------------

__global__ void k_edge1(const int* __restrict__ src, const int* __restrict__ dst,
                        const float* __restrict__ w, float* __restrict__ deg,
                        int* __restrict__ cnt) {
  const int e = blockIdx.x * blockDim.x + threadIdx.x;
  if (e >= EE) return;
  atomicAdd(&deg[src[e]], w[e]);
  atomicAdd(&cnt[dst[e]], 1);
}

__global__ void k_dinv(const float* __restrict__ deg, float* __restrict__ dinv) {
  const int i = blockIdx.x * blockDim.x + threadIdx.x;
  if (i < NN) {
    const float d = deg[i];
    dinv[i] = (d > 0.f) ? rsqrtf(fmaxf(d, 1e-30f)) : 0.f;
  }
}

// single-block exclusive scan over cnt[NN] -> off[NN+1], also copies to cur[]
__global__ void k_scan(const int* __restrict__ cnt, int* __restrict__ off,
                       int* __restrict__ cur) {
  __shared__ int wsum[16];
  __shared__ int wpre[16];
  __shared__ int total;
  __shared__ int carry;
  const int tid = threadIdx.x;
  const int lane = tid & 63, wv = tid >> 6;
  if (tid == 0) carry = 0;
  __syncthreads();
  for (int base = 0; base < NN; base += 1024) {
    const int i = base + tid;
    const int v = (i < NN) ? cnt[i] : 0;
    int x = v;
#pragma unroll
    for (int d = 1; d < 64; d <<= 1) {
      const int y = __shfl_up(x, d, 64);
      if (lane >= d) x += y;
    }
    if (lane == 63) wsum[wv] = x;
    __syncthreads();
    if (tid == 0) {
      int s = 0;
#pragma unroll
      for (int u = 0; u < 16; ++u) { wpre[u] = s; s += wsum[u]; }
      total = s;
    }
    __syncthreads();
    if (i < NN) {
      const int excl = carry + wpre[wv] + x - v;
      off[i] = excl;
      cur[i] = excl;
    }
    const int tt = total;
    __syncthreads();
    if (tid == 0) carry += tt;
    __syncthreads();
  }
  if (tid == 0) off[NN] = carry;
}

__global__ void k_edge2(const int* __restrict__ src, const int* __restrict__ dst,
                        const float* __restrict__ w, const float* __restrict__ dinv,
                        int* __restrict__ cur, int* __restrict__ srcs,
                        float* __restrict__ wns) {
  const int e = blockIdx.x * blockDim.x + threadIdx.x;
  if (e >= EE) return;
  const int s = src[e], d = dst[e];
  const int p = atomicAdd(&cur[d], 1);
  srcs[p] = s;
  wns[p] = -w[e] * dinv[s] * dinv[d];
}

// out[node][f] = alpha * sum_{p} wn[p] * vin[srcs[p]][f]  (- vsub[node][f] if vsub)
__global__ void k_gather(const float* __restrict__ vin, const float* __restrict__ vsub,
                         const float alpha, const int* __restrict__ off,
                         const int* __restrict__ srcs, const float* __restrict__ wns,
                         float* __restrict__ vout) {
  const int node = blockIdx.x;
  const int f = threadIdx.x;
  const int p0 = off[node], p1 = off[node + 1];
  float a0 = 0.f, a1 = 0.f, a2 = 0.f, a3 = 0.f;
  int p = p0;
  for (; p + 3 < p1; p += 4) {
    const int s0 = srcs[p], s1 = srcs[p + 1], s2 = srcs[p + 2], s3 = srcs[p + 3];
    const float w0 = wns[p], w1 = wns[p + 1], w2 = wns[p + 2], w3 = wns[p + 3];
    a0 = fmaf(w0, vin[s0 * HH + f], a0);
    a1 = fmaf(w1, vin[s1 * HH + f], a1);
    a2 = fmaf(w2, vin[s2 * HH + f], a2);
    a3 = fmaf(w3, vin[s3 * HH + f], a3);
  }
  for (; p < p1; ++p) a0 = fmaf(wns[p], vin[srcs[p] * HH + f], a0);
  float r = alpha * ((a0 + a1) + (a2 + a3));
  if (vsub) r -= vsub[node * HH + f];
  vout[node * HH + f] = r;
}

// ---------------- dense stage ----------------
// B_glob layout: 16 k-tiles; tile ks (k in [32ks,32ks+32)) is [512 cols][40 bf16]
// (pad 40 for LDS bank spread); entry [c][dk] = B[32ks+dk][c], where
// B[k][c]: g=c>>7, hc=c&127, kb=k>>7, r=k&127:
//   kb==0 -> W_g[r][hc] ; else theta_g[kb-1][r][hc]
__global__ void k_buildB(const float* __restrict__ Wi, const float* __restrict__ Wf,
                         const float* __restrict__ Wc, const float* __restrict__ Wo,
                         const float* __restrict__ Ti, const float* __restrict__ Tf,
                         const float* __restrict__ Tc, const float* __restrict__ To,
                         unsigned short* __restrict__ bglob) {
  const int e = blockIdx.x * blockDim.x + threadIdx.x;  // 0..262143
  const int k = e >> 9, c = e & 511;
  const int g = c >> 7, hc = c & 127;
  const int kb = k >> 7, r = k & 127;
  const float* Wg = (g == 0) ? Wi : (g == 1) ? Wf : (g == 2) ? Wc : Wo;
  const float* Tg = (g == 0) ? Ti : (g == 1) ? Tf : (g == 2) ? Tc : To;
  const float v = (kb == 0) ? Wg[r * 128 + hc] : Tg[(kb - 1) * 16384 + r * 128 + hc];
  bglob[((k >> 5) * 512 + c) * 40 + (k & 31)] = f2bf(v);
}

// A = [x | h | Tx1 | Tx2] (N x 512), out = A @ B (N x 512) -> fused LSTM epilogue.
// Block: 256 thr (4 waves), 64 rows; wave w owns rows [w*16, w*16+16), all 512 cols.
__global__ __launch_bounds__(256, 2) void k_gemm(
    const float* __restrict__ x, const float* __restrict__ h,
    const float* __restrict__ tx1, const float* __restrict__ tx2,
    const unsigned short* __restrict__ bglob, const float* __restrict__ c_prev,
    const float* __restrict__ b_i, const float* __restrict__ b_f,
    const float* __restrict__ b_c, const float* __restrict__ b_o,
    const float* __restrict__ w_ci, const float* __restrict__ w_cf,
    const float* __restrict__ w_co, float* __restrict__ h_out,
    float* __restrict__ c_out) {
  __shared__ char smem[40960];
  const int tid = threadIdx.x;
  const int lane = tid & 63;
  const int wid = tid >> 6;
  const int kg = lane >> 4;   // 0..3 (k-group)
  const int lm = lane & 15;
  const int m0 = blockIdx.x * 64;
  const int arow = m0 + wid * 16 + lm;

  f32x4 acc[32];
#pragma unroll
  for (int i = 0; i < 32; ++i) acc[i] = (f32x4){0.f, 0.f, 0.f, 0.f};

  for (int ks = 0; ks < 16; ++ks) {
    __syncthreads();  // previous tile's LDS reads done
    // stage B k-tile (40960 B) straight into LDS
    const char* gtile = (const char*)bglob + ks * 40960;
#pragma unroll
    for (int i = 0; i < 10; ++i) {
      const int chunk = i * 4 + wid;
      async_copy16(gtile + chunk * 1024 + lane * 16, (char*)smem + chunk * 1024);
    }
    // A fragment: row = arow, k = 32*ks + kg*8 + e  (f32 -> bf16)
    const float* mp = (ks < 4) ? x : (ks < 8) ? h : (ks < 12) ? tx1 : tx2;
    const int colb = (ks & 3) * 32 + kg * 8;
    float av[8];
    if (arow < NN) {
      const float* ap = mp + arow * 128 + colb;
      *(f32x4*)(av) = *(const f32x4*)(ap);
      *(f32x4*)(av + 4) = *(const f32x4*)(ap + 4);
    } else {
#pragma unroll
      for (int e = 0; e < 8; ++e) av[e] = 0.f;
    }
    bf16x8 afrag;
#pragma unroll
    for (int e = 0; e < 8; ++e) afrag[e] = (short)f2bf(av[e]);
    __syncthreads();  // staging complete (vmcnt drained by barrier)
#pragma unroll
    for (int cf = 0; cf < 32; ++cf) {
      const int c = cf * 16 + lm;
      const bf16x8 bfrag = *(const bf16x8*)(smem + c * 80 + kg * 16);
      acc[cf] = __builtin_amdgcn_mfma_f32_16x16x32_bf16(afrag, bfrag, acc[cf], 0, 0, 0);
    }
  }

  // Epilogue: lane holds, for rows r0..r0+3 and hc = 16t+lm:
  //   pre_i = acc[t], pre_f = acc[t+8], pre_c = acc[t+16], pre_o = acc[t+24]
  const int r0 = m0 + wid * 16 + kg * 4;
#pragma unroll
  for (int t = 0; t < 8; ++t) {
    const int hc = t * 16 + lm;
    const float bi = b_i[hc], bfv = b_f[hc], bc = b_c[hc], bo = b_o[hc];
    const float wci = w_ci[hc], wcf = w_cf[hc], wco = w_co[hc];
#pragma unroll
    for (int j = 0; j < 4; ++j) {
      const int node = r0 + j;
      if (node < NN) {
        const float cp = c_prev[node * 128 + hc];
        const float pi = acc[t][j] + bi + wci * cp;
        const float pf = acc[t + 8][j] + bfv + wcf * cp;
        const float pc = acc[t + 16][j] + bc;
        const float po = acc[t + 24][j] + bo;
        const float ig = 1.f / (1.f + __expf(-pi));
        const float fg = 1.f / (1.f + __expf(-pf));
        const float ct = fg * cp + ig * tanhf(pc);
        const float og = 1.f / (1.f + __expf(-(po + wco * ct)));
        h_out[node * 128 + hc] = og * tanhf(ct);
        c_out[node * 128 + hc] = ct;
      }
    }
  }
}

// ---------------- launcher ----------------

extern "C" void kernel_launch(void* const* d_in, const int* in_sizes, int n_in,
                              void* d_out, int out_size, void* d_ws, size_t ws_size,
                              hipStream_t stream) {
  const float* x_t    = (const float*)d_in[0];
  const float* h_prev = (const float*)d_in[1];
  const float* c_prev = (const float*)d_in[2];
  const float* ew     = (const float*)d_in[3];
  const int*   eidx   = (const int*)d_in[4];
  const float* Wi = (const float*)d_in[5];
  const float* Wf = (const float*)d_in[6];
  const float* Wc = (const float*)d_in[7];
  const float* Wo = (const float*)d_in[8];
  const float* Ti = (const float*)d_in[9];
  const float* Tf = (const float*)d_in[10];
  const float* Tc = (const float*)d_in[11];
  const float* To = (const float*)d_in[12];
  const float* bi = (const float*)d_in[13];
  const float* bf = (const float*)d_in[14];
  const float* bc = (const float*)d_in[15];
  const float* bo = (const float*)d_in[16];
  const float* wci = (const float*)d_in[17];
  const float* wcf = (const float*)d_in[18];
  const float* wco = (const float*)d_in[19];

  char* ws = (char*)d_ws;
  float* deg  = (float*)(ws + 0);
  int*   cnt  = (int*)(ws + 200192);
  float* dinv = (float*)(ws + 400384);
  int*   off  = (int*)(ws + 600576);
  int*   cur  = (int*)(ws + 800768);
  int*   srcs = (int*)(ws + 1000960);
  float* wns  = (float*)(ws + 4201216);
  unsigned short* bglob = (unsigned short*)(ws + 7401472);

  float* out = (float*)d_out;
  float* tx1 = out;            // reuse d_out as Tx1/Tx2 scratch, overwritten by h_t/c_t
  float* tx2 = out + NN * HH;

  const int* esrc = eidx;
  const int* edst = eidx + EE;

  hipMemsetAsync(ws, 0, 600576, stream);  // deg + cnt

  k_buildB<<<1024, 256, 0, stream>>>(Wi, Wf, Wc, Wo, Ti, Tf, Tc, To, bglob);
  k_edge1<<<(EE + 255) / 256, 256, 0, stream>>>(esrc, edst, ew, deg, cnt);
  k_dinv<<<(NN + 255) / 256, 256, 0, stream>>>(deg, dinv);
  k_scan<<<1, 1024, 0, stream>>>(cnt, off, cur);
  k_edge2<<<(EE + 255) / 256, 256, 0, stream>>>(esrc, edst, ew, dinv, cur, srcs, wns);
  k_gather<<<NN, 128, 0, stream>>>(h_prev, nullptr, 1.f, off, srcs, wns, tx1);
  k_gather<<<NN, 128, 0, stream>>>(tx1, h_prev, 2.f, off, srcs, wns, tx2);
  k_gemm<<<(NN + 63) / 64, 256, 0, stream>>>(x_t, h_prev, tx1, tx2, bglob, c_prev,
                                             bi, bf, bc, bo, wci, wcf, wco,
                                             tx1, tx2);
}

// Round 2
// 327.711 us; speedup vs baseline: 1.1974x; 1.1974x over previous
//
#include <hip/hip_runtime.h>

#define NN 50000
#define EE 800000
#define HH 128

typedef float f32x4 __attribute__((ext_vector_type(4)));
typedef short bf16x8 __attribute__((ext_vector_type(8)));
typedef unsigned short u16x8 __attribute__((ext_vector_type(8)));

__device__ __forceinline__ unsigned short f2bf(float f) {
  unsigned int u = __float_as_uint(f);
  u += 0x7fffu + ((u >> 16) & 1u);
  return (unsigned short)(u >> 16);
}

__device__ __forceinline__ void async_copy16(const void* g, void* l) {
  __builtin_amdgcn_global_load_lds(
      (const __attribute__((address_space(1))) unsigned int*)g,
      (__attribute__((address_space(3))) unsigned int*)l, 16, 0, 0);
}

// ---------------- graph preprocessing ----------------

__global__ void k_edge1(const int* __restrict__ src, const int* __restrict__ dst,
                        const float* __restrict__ w, float* __restrict__ deg,
                        int* __restrict__ cnt) {
  const int e = blockIdx.x * blockDim.x + threadIdx.x;
  if (e >= EE) return;
  atomicAdd(&deg[src[e]], w[e]);
  atomicAdd(&cnt[dst[e]], 1);
}

__global__ void k_dinv(const float* __restrict__ deg, float* __restrict__ dinv) {
  const int i = blockIdx.x * blockDim.x + threadIdx.x;
  if (i < NN) {
    const float d = deg[i];
    dinv[i] = (d > 0.f) ? rsqrtf(fmaxf(d, 1e-30f)) : 0.f;
  }
}

// exclusive scan helper over 256 threads; also returns block total
__device__ __forceinline__ int block_scan_excl_256(int v, int* total) {
  __shared__ int wsum[4];
  const int tid = threadIdx.x;
  const int lane = tid & 63, wv = tid >> 6;
  int x = v;
#pragma unroll
  for (int d = 1; d < 64; d <<= 1) {
    const int y = __shfl_up(x, d, 64);
    if (lane >= d) x += y;
  }
  if (lane == 63) wsum[wv] = x;
  __syncthreads();
  int pre = 0, tot = 0;
#pragma unroll
  for (int u = 0; u < 4; ++u) {
    const int s = wsum[u];
    pre += (u < wv) ? s : 0;
    tot += s;
  }
  *total = tot;
  return pre + x - v;
}

__global__ void k_scan1(const int* __restrict__ cnt, int* __restrict__ bsum) {
  const int i = blockIdx.x * 256 + threadIdx.x;
  const int v = (i < NN) ? cnt[i] : 0;
  int tot;
  block_scan_excl_256(v, &tot);
  if (threadIdx.x == 0) bsum[blockIdx.x] = tot;
}

__global__ void k_scan2(const int* __restrict__ bsum, int* __restrict__ boff,
                        const int nb) {
  const int t = threadIdx.x;
  const int v = (t < nb) ? bsum[t] : 0;
  int tot;
  const int excl = block_scan_excl_256(v, &tot);
  if (t <= nb) boff[t] = excl;  // boff[nb] = grand total
}

__global__ void k_scan3(const int* __restrict__ cnt, const int* __restrict__ boff,
                        int* __restrict__ off, int* __restrict__ cur) {
  const int i = blockIdx.x * 256 + threadIdx.x;
  const int v = (i < NN) ? cnt[i] : 0;
  int tot;
  const int excl = block_scan_excl_256(v, &tot) + boff[blockIdx.x];
  if (i < NN) {
    off[i] = excl;
    cur[i] = excl;
  }
  if (i == NN) off[NN] = excl;
}

__global__ void k_edge2(const int* __restrict__ src, const int* __restrict__ dst,
                        const float* __restrict__ w, const float* __restrict__ dinv,
                        int* __restrict__ cur, int2* __restrict__ ed) {
  const int e = blockIdx.x * blockDim.x + threadIdx.x;
  if (e >= EE) return;
  const int s = src[e], d = dst[e];
  const int p = atomicAdd(&cur[d], 1);
  int2 rec;
  rec.x = s;
  rec.y = __float_as_int(-w[e] * dinv[s] * dinv[d]);
  ed[p] = rec;
}

// out[node][f] = alpha * sum_{p} wn[p] * vin[srcs[p]][f]  (- vsub[node][f] if vsub)
__global__ void k_gather(const float* __restrict__ vin, const float* __restrict__ vsub,
                         const float alpha, const int* __restrict__ off,
                         const int2* __restrict__ ed, float* __restrict__ vout) {
  const int node = blockIdx.x;
  const int f = threadIdx.x;
  const int p0 = off[node], p1 = off[node + 1];
  float a0 = 0.f, a1 = 0.f, a2 = 0.f, a3 = 0.f;
  int p = p0;
  for (; p + 3 < p1; p += 4) {
    const int2 e0 = ed[p], e1 = ed[p + 1], e2 = ed[p + 2], e3 = ed[p + 3];
    a0 = fmaf(__int_as_float(e0.y), vin[e0.x * HH + f], a0);
    a1 = fmaf(__int_as_float(e1.y), vin[e1.x * HH + f], a1);
    a2 = fmaf(__int_as_float(e2.y), vin[e2.x * HH + f], a2);
    a3 = fmaf(__int_as_float(e3.y), vin[e3.x * HH + f], a3);
  }
  for (; p < p1; ++p) {
    const int2 e0 = ed[p];
    a0 = fmaf(__int_as_float(e0.y), vin[e0.x * HH + f], a0);
  }
  float r = alpha * ((a0 + a1) + (a2 + a3));
  if (vsub) r -= vsub[node * HH + f];
  vout[node * HH + f] = r;
}

// ---------------- dense stage ----------------
// bglob layout: MFMA-fragment-native. 16 k-tiles (ks); per tile 32 frags (cf);
// per frag 64 lanes x 8 bf16 (16B). cf = w*8 + hl*4 + g ; lane = kg*16 + lm.
// Element dk of (ks,cf,lane) = B[k][c] with k = ks*32+kg*8+dk,
// c = g*128 + hc, hc = (w*2+hl)*16 + lm, where
// B[k][c]: kb=k>>7, r=k&127 : kb==0 -> W_g[r][hc] else theta_g[kb-1][r][hc]
__global__ void k_buildB(const float* __restrict__ Wi, const float* __restrict__ Wf,
                         const float* __restrict__ Wc, const float* __restrict__ Wo,
                         const float* __restrict__ Ti, const float* __restrict__ Tf,
                         const float* __restrict__ Tc, const float* __restrict__ To,
                         unsigned short* __restrict__ bglob) {
  const int t = blockIdx.x * blockDim.x + threadIdx.x;  // 0..32767
  const int ks = t >> 11;
  const int cf = (t >> 6) & 31;
  const int lane = t & 63;
  const int w = cf >> 3, hl = (cf >> 2) & 1, g = cf & 3;
  const int kg = lane >> 4, lm = lane & 15;
  const int hc = (w * 2 + hl) * 16 + lm;
  const float* Wg = (g == 0) ? Wi : (g == 1) ? Wf : (g == 2) ? Wc : Wo;
  const float* Tg = (g == 0) ? Ti : (g == 1) ? Tf : (g == 2) ? Tc : To;
  u16x8 out;
#pragma unroll
  for (int dk = 0; dk < 8; ++dk) {
    const int k = ks * 32 + kg * 8 + dk;
    const int kb = k >> 7, r = k & 127;
    const float v = (kb == 0) ? Wg[r * 128 + hc] : Tg[(kb - 1) * 16384 + r * 128 + hc];
    out[dk] = f2bf(v);
  }
  *(u16x8*)(bglob + t * 8) = out;
}

// A = [x | h | Tx1 | Tx2] (N x 512), out = A @ B -> fused LSTM epilogue.
// Block: 256 thr (4 waves), 64 rows, K=512 in 16 steps. Wave w owns 32 hc cols
// (hb = 2w, 2w+1), ALL 4 gates (gate-interleaved B layout) -> per-lane epilogue.
__global__ __launch_bounds__(256, 2) void k_gemm(
    const float* __restrict__ x, const float* __restrict__ h,
    const float* __restrict__ tx1, const float* __restrict__ tx2,
    const unsigned short* __restrict__ bglob, const float* __restrict__ c_prev,
    const float* __restrict__ b_i, const float* __restrict__ b_f,
    const float* __restrict__ b_c, const float* __restrict__ b_o,
    const float* __restrict__ w_ci, const float* __restrict__ w_cf,
    const float* __restrict__ w_co, float* __restrict__ h_out,
    float* __restrict__ c_out) {
  // per buffer: B frags 16384 shorts (32KB) + A frags 2048 shorts (4KB)
  __shared__ short smem[2][18432];
  const int tid = threadIdx.x;
  const int lane = tid & 63;
  const int wid = tid >> 6;
  const int kg = lane >> 4;
  const int lm = lane & 15;
  const int m0 = blockIdx.x * 64;
  const int arow = m0 + wid * 16 + lm;  // row this thread stages

  f32x4 acc[32];  // acc[rf*8 + hl*4 + g]
#pragma unroll
  for (int i = 0; i < 32; ++i) acc[i] = (f32x4){0.f, 0.f, 0.f, 0.f};

  auto stage = [&](int ks, int buf) {
    // B tile: 32KB via async global->LDS, fragment-contiguous
    const unsigned short* gtile = bglob + ks * 16384;
    short* bl = &smem[buf][0];
#pragma unroll
    for (int r = 0; r < 8; ++r)
      async_copy16(gtile + r * 2048 + tid * 8, bl + r * 2048 + tid * 8);
    // A tile: rf = wid, f32 -> bf16 -> ds_write (fragment-contiguous)
    const float* mp = (ks < 4) ? x : (ks < 8) ? h : (ks < 12) ? tx1 : tx2;
    const int colb = (ks & 3) * 32 + kg * 8;
    float av[8];
    if (arow < NN) {
      const float* ap = mp + arow * 128 + colb;
      *(f32x4*)(av) = *(const f32x4*)(ap);
      *(f32x4*)(av + 4) = *(const f32x4*)(ap + 4);
    } else {
#pragma unroll
      for (int e = 0; e < 8; ++e) av[e] = 0.f;
    }
    bf16x8 afrag;
#pragma unroll
    for (int e = 0; e < 8; ++e) afrag[e] = (short)f2bf(av[e]);
    *(bf16x8*)(&smem[buf][16384 + tid * 8]) = afrag;
  };

  stage(0, 0);
  __syncthreads();

  for (int ks = 0; ks < 16; ++ks) {
    const int buf = ks & 1;
    if (ks < 15) stage(ks + 1, buf ^ 1);
    bf16x8 a[4], b[8];
#pragma unroll
    for (int rf = 0; rf < 4; ++rf)
      a[rf] = *(const bf16x8*)(&smem[buf][16384 + rf * 512 + lane * 8]);
#pragma unroll
    for (int i = 0; i < 8; ++i)
      b[i] = *(const bf16x8*)(&smem[buf][(wid * 8 + i) * 512 + lane * 8]);
#pragma unroll
    for (int rf = 0; rf < 4; ++rf)
#pragma unroll
      for (int i = 0; i < 8; ++i)
        acc[rf * 8 + i] =
            __builtin_amdgcn_mfma_f32_16x16x32_bf16(a[rf], b[i], acc[rf * 8 + i], 0, 0, 0);
    __syncthreads();
  }

  // Epilogue: lane holds all 4 gates for node = m0+rf*16+kg*4+reg, hc=(2*wid+hl)*16+lm
#pragma unroll
  for (int hl = 0; hl < 2; ++hl) {
    const int hc = (wid * 2 + hl) * 16 + lm;
    const float bi = b_i[hc], bfv = b_f[hc], bc = b_c[hc], bo = b_o[hc];
    const float wci = w_ci[hc], wcf = w_cf[hc], wco = w_co[hc];
#pragma unroll
    for (int rf = 0; rf < 4; ++rf) {
#pragma unroll
      for (int reg = 0; reg < 4; ++reg) {
        const int node = m0 + rf * 16 + kg * 4 + reg;
        if (node < NN) {
          const float cp = c_prev[node * 128 + hc];
          const float pi = acc[rf * 8 + hl * 4 + 0][reg] + bi + wci * cp;
          const float pf = acc[rf * 8 + hl * 4 + 1][reg] + bfv + wcf * cp;
          const float pc = acc[rf * 8 + hl * 4 + 2][reg] + bc;
          const float po = acc[rf * 8 + hl * 4 + 3][reg] + bo;
          const float ig = 1.f / (1.f + __expf(-pi));
          const float fg = 1.f / (1.f + __expf(-pf));
          const float ct = fg * cp + ig * tanhf(pc);
          const float og = 1.f / (1.f + __expf(-(po + wco * ct)));
          h_out[node * 128 + hc] = og * tanhf(ct);
          c_out[node * 128 + hc] = ct;
        }
      }
    }
  }
}

// ---------------- launcher ----------------

extern "C" void kernel_launch(void* const* d_in, const int* in_sizes, int n_in,
                              void* d_out, int out_size, void* d_ws, size_t ws_size,
                              hipStream_t stream) {
  const float* x_t    = (const float*)d_in[0];
  const float* h_prev = (const float*)d_in[1];
  const float* c_prev = (const float*)d_in[2];
  const float* ew     = (const float*)d_in[3];
  const int*   eidx   = (const int*)d_in[4];
  const float* Wi = (const float*)d_in[5];
  const float* Wf = (const float*)d_in[6];
  const float* Wc = (const float*)d_in[7];
  const float* Wo = (const float*)d_in[8];
  const float* Ti = (const float*)d_in[9];
  const float* Tf = (const float*)d_in[10];
  const float* Tc = (const float*)d_in[11];
  const float* To = (const float*)d_in[12];
  const float* bi = (const float*)d_in[13];
  const float* bf = (const float*)d_in[14];
  const float* bc = (const float*)d_in[15];
  const float* bo = (const float*)d_in[16];
  const float* wci = (const float*)d_in[17];
  const float* wcf = (const float*)d_in[18];
  const float* wco = (const float*)d_in[19];

  char* ws = (char*)d_ws;
  float* deg  = (float*)(ws + 0);        // 200192
  int*   cnt  = (int*)(ws + 200192);     // 200192
  float* dinv = (float*)(ws + 400384);   // 200192
  int*   off  = (int*)(ws + 600576);     // 200704 (50001 ints)
  int*   cur  = (int*)(ws + 801280);     // 200704
  int*   bsum = (int*)(ws + 1001984);    // 1024
  int*   boff = (int*)(ws + 1003008);    // 1024
  int2*  ed   = (int2*)(ws + 1004032);   // 6400000
  unsigned short* bglob = (unsigned short*)(ws + 7404032);  // 524288 -> ends 7928320

  float* out = (float*)d_out;
  float* tx1 = out;            // reuse d_out as Tx1/Tx2 scratch, overwritten at epilogue
  float* tx2 = out + NN * HH;

  const int* esrc = eidx;
  const int* edst = eidx + EE;

  const int NB = (NN + 255) / 256;  // 196

  hipMemsetAsync(ws, 0, 400384, stream);  // deg + cnt

  k_buildB<<<128, 256, 0, stream>>>(Wi, Wf, Wc, Wo, Ti, Tf, Tc, To, bglob);
  k_edge1<<<(EE + 255) / 256, 256, 0, stream>>>(esrc, edst, ew, deg, cnt);
  k_dinv<<<NB, 256, 0, stream>>>(deg, dinv);
  k_scan1<<<NB, 256, 0, stream>>>(cnt, bsum);
  k_scan2<<<1, 256, 0, stream>>>(bsum, boff, NB);
  k_scan3<<<NB, 256, 0, stream>>>(cnt, boff, off, cur);
  k_edge2<<<(EE + 255) / 256, 256, 0, stream>>>(esrc, edst, ew, dinv, cur, ed);
  k_gather<<<NN, 128, 0, stream>>>(h_prev, nullptr, 1.f, off, ed, tx1);
  k_gather<<<NN, 128, 0, stream>>>(tx1, h_prev, 2.f, off, ed, tx2);
  k_gemm<<<(NN + 63) / 64, 256, 0, stream>>>(x_t, h_prev, tx1, tx2, bglob, c_prev,
                                             bi, bf, bc, bo, wci, wcf, wco,
                                             tx1, tx2);
}

// Round 3
// 299.729 us; speedup vs baseline: 1.3092x; 1.0934x over previous
//
#include <hip/hip_runtime.h>

#define NN 50000
#define EE 800000

typedef float f32x4 __attribute__((ext_vector_type(4)));
typedef short bf16x8 __attribute__((ext_vector_type(8)));
typedef unsigned short u16x8 __attribute__((ext_vector_type(8)));

__device__ __forceinline__ unsigned short f2bf(float f) {
  unsigned int u = __float_as_uint(f);
  u += 0x7fffu + ((u >> 16) & 1u);
  return (unsigned short)(u >> 16);
}
__device__ __forceinline__ float bf2f(unsigned short u) {
  return __uint_as_float(((unsigned int)u) << 16);
}

// ---------------- phase 1: buildB + h->bf16 + edge pass 1 (fused) ----------------
// bglob layout (fragment-native, as round 2): frag (ks,cf) at 1KB granularity;
// cf = w*8 + hl*4 + g; lane = kg*16+lm; elem dk = B[ks*32+kg*8+dk][g*128+(w*2+hl)*16+lm]
__global__ void k_pre(const float* __restrict__ Wi, const float* __restrict__ Wf,
                      const float* __restrict__ Wc, const float* __restrict__ Wo,
                      const float* __restrict__ Ti, const float* __restrict__ Tf,
                      const float* __restrict__ Tc, const float* __restrict__ To,
                      unsigned short* __restrict__ bglob,
                      const float* __restrict__ h, char* __restrict__ outB,
                      const int* __restrict__ src, const int* __restrict__ dst,
                      const float* __restrict__ w, float* __restrict__ deg,
                      int* __restrict__ cnt) {
  const int b = blockIdx.x, tid = threadIdx.x;
  if (b < 128) {
    const int t = b * 256 + tid;
    const int ks = t >> 11;
    const int cf = (t >> 6) & 31;
    const int lane = t & 63;
    const int wv = cf >> 3, hl = (cf >> 2) & 1, g = cf & 3;
    const int kg = lane >> 4, lm = lane & 15;
    const int hc = (wv * 2 + hl) * 16 + lm;
    const float* Wg = (g == 0) ? Wi : (g == 1) ? Wf : (g == 2) ? Wc : Wo;
    const float* Tg = (g == 0) ? Ti : (g == 1) ? Tf : (g == 2) ? Tc : To;
    u16x8 out;
#pragma unroll
    for (int dk = 0; dk < 8; ++dk) {
      const int k = ks * 32 + kg * 8 + dk;
      const int kb = k >> 7, r = k & 127;
      const float v = (kb == 0) ? Wg[r * 128 + hc] : Tg[(kb - 1) * 16384 + r * 128 + hc];
      out[dk] = f2bf(v);
    }
    *(u16x8*)(bglob + t * 8) = out;
  } else if (b < 128 + 3125) {
    // h (N x 128 f32) -> hb bf16, stored at bytes [256,512) of each d_out h-row
    const int i = (b - 128) * 256 + tid;  // 0..799999, 8 elems each
    const float* hp = h + i * 8;
    const f32x4 v0 = *(const f32x4*)hp;
    const f32x4 v1 = *(const f32x4*)(hp + 4);
    u16x8 o;
#pragma unroll
    for (int e = 0; e < 4; ++e) o[e] = f2bf(v0[e]);
#pragma unroll
    for (int e = 0; e < 4; ++e) o[e + 4] = f2bf(v1[e]);
    *(u16x8*)(outB + (i >> 4) * 512 + 256 + (i & 15) * 16) = o;
  } else {
    const int e = (b - 3253) * 256 + tid;
    if (e < EE) {
      atomicAdd(&deg[src[e]], w[e]);
      atomicAdd(&cnt[dst[e]], 1);
    }
  }
}

// ---------------- scan machinery ----------------
__device__ __forceinline__ int block_scan_excl_256(int v, int* total) {
  __shared__ int wsum[4];
  const int tid = threadIdx.x;
  const int lane = tid & 63, wv = tid >> 6;
  int x = v;
#pragma unroll
  for (int d = 1; d < 64; d <<= 1) {
    const int y = __shfl_up(x, d, 64);
    if (lane >= d) x += y;
  }
  if (lane == 63) wsum[wv] = x;
  __syncthreads();
  int pre = 0, tot = 0;
#pragma unroll
  for (int u = 0; u < 4; ++u) {
    const int s = wsum[u];
    pre += (u < wv) ? s : 0;
    tot += s;
  }
  *total = tot;
  return pre + x - v;
}

// dinv (blocks 0..195) + scan1 (blocks 196..391)
__global__ void k_phase2(const float* __restrict__ deg, float* __restrict__ dinv,
                         const int* __restrict__ cnt, int* __restrict__ bsum) {
  if (blockIdx.x < 196) {
    const int i = blockIdx.x * 256 + threadIdx.x;
    if (i < NN) {
      const float d = deg[i];
      dinv[i] = (d > 0.f) ? rsqrtf(fmaxf(d, 1e-30f)) : 0.f;
    }
  } else {
    const int i = (blockIdx.x - 196) * 256 + threadIdx.x;
    const int v = (i < NN) ? cnt[i] : 0;
    int tot;
    block_scan_excl_256(v, &tot);
    if (threadIdx.x == 0) bsum[blockIdx.x - 196] = tot;
  }
}

__global__ void k_scan2(const int* __restrict__ bsum, int* __restrict__ boff,
                        const int nb) {
  const int t = threadIdx.x;
  const int v = (t < nb) ? bsum[t] : 0;
  int tot;
  const int excl = block_scan_excl_256(v, &tot);
  if (t <= nb) boff[t] = excl;
}

__global__ void k_scan3(const int* __restrict__ cnt, const int* __restrict__ boff,
                        int* __restrict__ off, int* __restrict__ cur) {
  const int i = blockIdx.x * 256 + threadIdx.x;
  const int v = (i < NN) ? cnt[i] : 0;
  int tot;
  const int excl = block_scan_excl_256(v, &tot) + boff[blockIdx.x];
  if (i < NN) {
    off[i] = excl;
    cur[i] = excl;
  }
  if (i == NN) off[NN] = excl;
}

__global__ void k_edge2(const int* __restrict__ src, const int* __restrict__ dst,
                        const float* __restrict__ w, const float* __restrict__ dinv,
                        int* __restrict__ cur, int2* __restrict__ ed) {
  const int e = blockIdx.x * blockDim.x + threadIdx.x;
  if (e >= EE) return;
  const int s = src[e], d = dst[e];
  const int p = atomicAdd(&cur[d], 1);
  int2 rec;
  rec.x = s;
  rec.y = __float_as_int(-w[e] * dinv[s] * dinv[d]);
  ed[p] = rec;
}

// ---------------- sparse gather (bf16 rows, 1 wave per node) ----------------
// row r of a bf16 matrix lives at base + r*512 (256B used); lane covers cols 2l,2l+1
__global__ __launch_bounds__(256) void k_gather(
    const char* __restrict__ vinB, const char* __restrict__ vsubB, const float alpha,
    const int* __restrict__ off, const int2* __restrict__ ed, char* __restrict__ voutB) {
  const int wid = threadIdx.x >> 6, lane = threadIdx.x & 63;
  const int node = blockIdx.x * 4 + wid;
  const int p0 = off[node], p1 = off[node + 1];
  const int lb = lane * 4;
  float ax0 = 0.f, ay0 = 0.f, ax1 = 0.f, ay1 = 0.f;
  float ax2 = 0.f, ay2 = 0.f, ax3 = 0.f, ay3 = 0.f;
  int p = p0;
  for (; p + 3 < p1; p += 4) {
    const int2 e0 = ed[p], e1 = ed[p + 1], e2 = ed[p + 2], e3 = ed[p + 3];
    const unsigned v0 = *(const unsigned*)(vinB + e0.x * 512 + lb);
    const unsigned v1 = *(const unsigned*)(vinB + e1.x * 512 + lb);
    const unsigned v2 = *(const unsigned*)(vinB + e2.x * 512 + lb);
    const unsigned v3 = *(const unsigned*)(vinB + e3.x * 512 + lb);
    const float w0 = __int_as_float(e0.y), w1 = __int_as_float(e1.y);
    const float w2 = __int_as_float(e2.y), w3 = __int_as_float(e3.y);
    ax0 = fmaf(w0, bf2f((unsigned short)v0), ax0);
    ay0 = fmaf(w0, bf2f((unsigned short)(v0 >> 16)), ay0);
    ax1 = fmaf(w1, bf2f((unsigned short)v1), ax1);
    ay1 = fmaf(w1, bf2f((unsigned short)(v1 >> 16)), ay1);
    ax2 = fmaf(w2, bf2f((unsigned short)v2), ax2);
    ay2 = fmaf(w2, bf2f((unsigned short)(v2 >> 16)), ay2);
    ax3 = fmaf(w3, bf2f((unsigned short)v3), ax3);
    ay3 = fmaf(w3, bf2f((unsigned short)(v3 >> 16)), ay3);
  }
  for (; p < p1; ++p) {
    const int2 e0 = ed[p];
    const unsigned v0 = *(const unsigned*)(vinB + e0.x * 512 + lb);
    const float w0 = __int_as_float(e0.y);
    ax0 = fmaf(w0, bf2f((unsigned short)v0), ax0);
    ay0 = fmaf(w0, bf2f((unsigned short)(v0 >> 16)), ay0);
  }
  float rx = alpha * ((ax0 + ax1) + (ax2 + ax3));
  float ry = alpha * ((ay0 + ay1) + (ay2 + ay3));
  if (vsubB) {
    const unsigned s = *(const unsigned*)(vsubB + node * 512 + lb);
    rx -= bf2f((unsigned short)s);
    ry -= bf2f((unsigned short)(s >> 16));
  }
  const unsigned ow = (unsigned)f2bf(rx) | ((unsigned)f2bf(ry) << 16);
  *(unsigned*)(voutB + node * 512 + lb) = ow;
}

// ---------------- dense stage: barrier-free, LDS-free MFMA GEMM ----------------
// A = [x(f32) | hb | tx1b | tx2b] (N x 512); block = 64 rows, 4 waves; wave w owns
// 32 hc-cols (all 4 gates); A frags read from global rows, B frags from L2-resident
// bglob. Register ping-pong double buffer; single barrier before epilogue.
__global__ __launch_bounds__(256, 2) void k_gemm(
    const float* __restrict__ x, const char* __restrict__ outB,
    const unsigned short* __restrict__ bglob, const float* __restrict__ c_prev,
    const float* __restrict__ b_i, const float* __restrict__ b_f,
    const float* __restrict__ b_c, const float* __restrict__ b_o,
    const float* __restrict__ w_ci, const float* __restrict__ w_cf,
    const float* __restrict__ w_co, float* __restrict__ h_out,
    float* __restrict__ c_out) {
  const int tid = threadIdx.x;
  const int lane = tid & 63;
  const int wid = tid >> 6;
  const int kg = lane >> 4;
  const int lm = lane & 15;
  const int m0 = blockIdx.x * 64;

  int rowc[4];
#pragma unroll
  for (int rf = 0; rf < 4; ++rf) {
    const int r = m0 + rf * 16 + lm;
    rowc[rf] = (r < NN) ? r : (NN - 1);
  }
  const char* hB = outB;                        // +256: hb, +0: tx1b
  const char* cB = outB + (long)NN * 512;       // +0: tx2b

  f32x4 acc[32];
#pragma unroll
  for (int i = 0; i < 32; ++i) acc[i] = (f32x4){0.f, 0.f, 0.f, 0.f};

  auto loadA = [&](int ks, bf16x8* a) {
#pragma unroll
    for (int rf = 0; rf < 4; ++rf) {
      if (ks < 4) {
        const float* ap = x + (long)rowc[rf] * 128 + ks * 32 + kg * 8;
        const f32x4 v0 = *(const f32x4*)ap;
        const f32x4 v1 = *(const f32x4*)(ap + 4);
        bf16x8 af;
#pragma unroll
        for (int e = 0; e < 4; ++e) af[e] = (short)f2bf(v0[e]);
#pragma unroll
        for (int e = 0; e < 4; ++e) af[e + 4] = (short)f2bf(v1[e]);
        a[rf] = af;
      } else {
        const char* base = (ks < 8) ? (hB + 256) : (ks < 12) ? hB : cB;
        a[rf] = *(const bf16x8*)(base + (long)rowc[rf] * 512 + (ks & 3) * 64 + kg * 16);
      }
    }
  };
  auto loadB = [&](int ks, bf16x8* bb) {
    const unsigned short* fp = bglob + ((ks * 32 + wid * 8) * 64 + lane) * 8;
#pragma unroll
    for (int i = 0; i < 8; ++i) bb[i] = *(const bf16x8*)(fp + i * 512);
  };

  bf16x8 a0[4], b0[8], a1[4], b1[8];
  loadA(0, a0);
  loadB(0, b0);
#pragma unroll
  for (int ks2 = 0; ks2 < 16; ks2 += 2) {
    loadA(ks2 + 1, a1);
    loadB(ks2 + 1, b1);
#pragma unroll
    for (int rf = 0; rf < 4; ++rf)
#pragma unroll
      for (int i = 0; i < 8; ++i)
        acc[rf * 8 + i] =
            __builtin_amdgcn_mfma_f32_16x16x32_bf16(a0[rf], b0[i], acc[rf * 8 + i], 0, 0, 0);
    if (ks2 + 2 < 16) {
      loadA(ks2 + 2, a0);
      loadB(ks2 + 2, b0);
    }
#pragma unroll
    for (int rf = 0; rf < 4; ++rf)
#pragma unroll
      for (int i = 0; i < 8; ++i)
        acc[rf * 8 + i] =
            __builtin_amdgcn_mfma_f32_16x16x32_bf16(a1[rf], b1[i], acc[rf * 8 + i], 0, 0, 0);
  }

  __syncthreads();  // all A-reads from d_out rows done before stores overwrite them

#pragma unroll
  for (int hl = 0; hl < 2; ++hl) {
    const int hc = (wid * 2 + hl) * 16 + lm;
    const float bi = b_i[hc], bfv = b_f[hc], bc = b_c[hc], bo = b_o[hc];
    const float wci = w_ci[hc], wcf = w_cf[hc], wco = w_co[hc];
#pragma unroll
    for (int rf = 0; rf < 4; ++rf) {
#pragma unroll
      for (int reg = 0; reg < 4; ++reg) {
        const int node = m0 + rf * 16 + kg * 4 + reg;
        if (node < NN) {
          const float cp = c_prev[node * 128 + hc];
          const float pi = acc[rf * 8 + hl * 4 + 0][reg] + bi + wci * cp;
          const float pf = acc[rf * 8 + hl * 4 + 1][reg] + bfv + wcf * cp;
          const float pc = acc[rf * 8 + hl * 4 + 2][reg] + bc;
          const float po = acc[rf * 8 + hl * 4 + 3][reg] + bo;
          const float ig = 1.f / (1.f + __expf(-pi));
          const float fg = 1.f / (1.f + __expf(-pf));
          const float ct = fg * cp + ig * tanhf(pc);
          const float og = 1.f / (1.f + __expf(-(po + wco * ct)));
          h_out[node * 128 + hc] = og * tanhf(ct);
          c_out[node * 128 + hc] = ct;
        }
      }
    }
  }
}

// ---------------- launcher ----------------

extern "C" void kernel_launch(void* const* d_in, const int* in_sizes, int n_in,
                              void* d_out, int out_size, void* d_ws, size_t ws_size,
                              hipStream_t stream) {
  const float* x_t    = (const float*)d_in[0];
  const float* h_prev = (const float*)d_in[1];
  const float* c_prev = (const float*)d_in[2];
  const float* ew     = (const float*)d_in[3];
  const int*   eidx   = (const int*)d_in[4];
  const float* Wi = (const float*)d_in[5];
  const float* Wf = (const float*)d_in[6];
  const float* Wc = (const float*)d_in[7];
  const float* Wo = (const float*)d_in[8];
  const float* Ti = (const float*)d_in[9];
  const float* Tf = (const float*)d_in[10];
  const float* Tc = (const float*)d_in[11];
  const float* To = (const float*)d_in[12];
  const float* bi = (const float*)d_in[13];
  const float* bf = (const float*)d_in[14];
  const float* bc = (const float*)d_in[15];
  const float* bo = (const float*)d_in[16];
  const float* wci = (const float*)d_in[17];
  const float* wcf = (const float*)d_in[18];
  const float* wco = (const float*)d_in[19];

  char* ws = (char*)d_ws;
  float* deg  = (float*)(ws + 0);        // 200192
  int*   cnt  = (int*)(ws + 200192);     // 200192
  float* dinv = (float*)(ws + 400384);   // 200192
  int*   off  = (int*)(ws + 600576);     // 200704
  int*   cur  = (int*)(ws + 801280);     // 200704
  int*   bsum = (int*)(ws + 1001984);    // 1024
  int*   boff = (int*)(ws + 1003008);    // 1024
  int2*  ed   = (int2*)(ws + 1004032);   // 6400000
  unsigned short* bglob = (unsigned short*)(ws + 7404032);  // 524288

  char* outB = (char*)d_out;  // h-rows: [tx1b 256B | hb 256B]; c-rows: [tx2b 256B | -]
  float* h_out = (float*)d_out;
  float* c_out = h_out + (long)NN * 128;

  const int* esrc = eidx;
  const int* edst = eidx + EE;

  hipMemsetAsync(ws, 0, 400384, stream);  // deg + cnt

  k_pre<<<6378, 256, 0, stream>>>(Wi, Wf, Wc, Wo, Ti, Tf, Tc, To, bglob,
                                  h_prev, outB, esrc, edst, ew, deg, cnt);
  k_phase2<<<392, 256, 0, stream>>>(deg, dinv, cnt, bsum);
  k_scan2<<<1, 256, 0, stream>>>(bsum, boff, 196);
  k_scan3<<<196, 256, 0, stream>>>(cnt, boff, off, cur);
  k_edge2<<<3125, 256, 0, stream>>>(esrc, edst, ew, dinv, cur, ed);
  k_gather<<<12500, 256, 0, stream>>>(outB + 256, nullptr, 1.f, off, ed, outB);
  k_gather<<<12500, 256, 0, stream>>>(outB, outB + 256, 2.f, off, ed,
                                      outB + (long)NN * 512);
  k_gemm<<<782, 256, 0, stream>>>(x_t, outB, bglob, c_prev,
                                  bi, bf, bc, bo, wci, wcf, wco, h_out, c_out);
}

// Round 4
// 282.460 us; speedup vs baseline: 1.3892x; 1.0611x over previous
//
#include <hip/hip_runtime.h>

#define NN 50000
#define EE 800000

typedef float f32x4 __attribute__((ext_vector_type(4)));
typedef short bf16x8 __attribute__((ext_vector_type(8)));
typedef unsigned short u16x8 __attribute__((ext_vector_type(8)));

__device__ __forceinline__ unsigned short f2bf(float f) {
  unsigned int u = __float_as_uint(f);
  u += 0x7fffu + ((u >> 16) & 1u);
  return (unsigned short)(u >> 16);
}
__device__ __forceinline__ float bf2f(unsigned short u) {
  return __uint_as_float(((unsigned int)u) << 16);
}

__device__ __forceinline__ void async_copy16(const void* g, void* l) {
  __builtin_amdgcn_global_load_lds(
      (const __attribute__((address_space(1))) unsigned int*)g,
      (__attribute__((address_space(3))) unsigned int*)l, 16, 0, 0);
}

// ---------------- phase 1: buildB + h->bf16 + x->bf16 + edge pass 1 ----------------
// bglob: fragment-native; frag (ks,cf) at 1KB; cf = w*8+hl*4+g; lane=kg*16+lm;
// elem dk = B[ks*32+kg*8+dk][g*128+(w*2+hl)*16+lm]
__global__ void k_pre(const float* __restrict__ Wi, const float* __restrict__ Wf,
                      const float* __restrict__ Wc, const float* __restrict__ Wo,
                      const float* __restrict__ Ti, const float* __restrict__ Tf,
                      const float* __restrict__ Tc, const float* __restrict__ To,
                      unsigned short* __restrict__ bglob,
                      const float* __restrict__ h, const float* __restrict__ x,
                      char* __restrict__ outB,
                      const int* __restrict__ src, const int* __restrict__ dst,
                      const float* __restrict__ w, float* __restrict__ deg,
                      int* __restrict__ cnt) {
  const int b = blockIdx.x, tid = threadIdx.x;
  if (b < 128) {
    const int t = b * 256 + tid;
    const int ks = t >> 11;
    const int cf = (t >> 6) & 31;
    const int lane = t & 63;
    const int wv = cf >> 3, hl = (cf >> 2) & 1, g = cf & 3;
    const int kg = lane >> 4, lm = lane & 15;
    const int hc = (wv * 2 + hl) * 16 + lm;
    const float* Wg = (g == 0) ? Wi : (g == 1) ? Wf : (g == 2) ? Wc : Wo;
    const float* Tg = (g == 0) ? Ti : (g == 1) ? Tf : (g == 2) ? Tc : To;
    u16x8 out;
#pragma unroll
    for (int dk = 0; dk < 8; ++dk) {
      const int k = ks * 32 + kg * 8 + dk;
      const int kb = k >> 7, r = k & 127;
      const float v = (kb == 0) ? Wg[r * 128 + hc] : Tg[(kb - 1) * 16384 + r * 128 + hc];
      out[dk] = f2bf(v);
    }
    *(u16x8*)(bglob + t * 8) = out;
  } else if (b < 3253) {
    // hb: h-row bytes [256,512)
    const int i = (b - 128) * 256 + tid;
    const float* hp = h + i * 8;
    const f32x4 v0 = *(const f32x4*)hp;
    const f32x4 v1 = *(const f32x4*)(hp + 4);
    u16x8 o;
#pragma unroll
    for (int e = 0; e < 4; ++e) o[e] = f2bf(v0[e]);
#pragma unroll
    for (int e = 0; e < 4; ++e) o[e + 4] = f2bf(v1[e]);
    *(u16x8*)(outB + (i >> 4) * 512 + 256 + (i & 15) * 16) = o;
  } else if (b < 6378) {
    // xb: c-row bytes [256,512)
    const int i = (b - 3253) * 256 + tid;
    const float* xp = x + i * 8;
    const f32x4 v0 = *(const f32x4*)xp;
    const f32x4 v1 = *(const f32x4*)(xp + 4);
    u16x8 o;
#pragma unroll
    for (int e = 0; e < 4; ++e) o[e] = f2bf(v0[e]);
#pragma unroll
    for (int e = 0; e < 4; ++e) o[e + 4] = f2bf(v1[e]);
    *(u16x8*)(outB + (long)NN * 512 + (i >> 4) * 512 + 256 + (i & 15) * 16) = o;
  } else {
    const int e = (b - 6378) * 256 + tid;
    if (e < EE) {
      atomicAdd(&deg[src[e]], w[e]);
      atomicAdd(&cnt[dst[e]], 1);
    }
  }
}

// ---------------- scan machinery ----------------
__device__ __forceinline__ int block_scan_excl_256(int v, int* total) {
  __shared__ int wsum[4];
  const int tid = threadIdx.x;
  const int lane = tid & 63, wv = tid >> 6;
  int x = v;
#pragma unroll
  for (int d = 1; d < 64; d <<= 1) {
    const int y = __shfl_up(x, d, 64);
    if (lane >= d) x += y;
  }
  if (lane == 63) wsum[wv] = x;
  __syncthreads();
  int pre = 0, tot = 0;
#pragma unroll
  for (int u = 0; u < 4; ++u) {
    const int s = wsum[u];
    pre += (u < wv) ? s : 0;
    tot += s;
  }
  *total = tot;
  return pre + x - v;
}

__global__ void k_phase2(const float* __restrict__ deg, float* __restrict__ dinv,
                         const int* __restrict__ cnt, int* __restrict__ bsum) {
  if (blockIdx.x < 196) {
    const int i = blockIdx.x * 256 + threadIdx.x;
    if (i < NN) {
      const float d = deg[i];
      dinv[i] = (d > 0.f) ? rsqrtf(fmaxf(d, 1e-30f)) : 0.f;
    }
  } else {
    const int i = (blockIdx.x - 196) * 256 + threadIdx.x;
    const int v = (i < NN) ? cnt[i] : 0;
    int tot;
    block_scan_excl_256(v, &tot);
    if (threadIdx.x == 0) bsum[blockIdx.x - 196] = tot;
  }
}

__global__ void k_scan2(const int* __restrict__ bsum, int* __restrict__ boff,
                        const int nb) {
  const int t = threadIdx.x;
  const int v = (t < nb) ? bsum[t] : 0;
  int tot;
  const int excl = block_scan_excl_256(v, &tot);
  if (t <= nb) boff[t] = excl;
}

__global__ void k_scan3(const int* __restrict__ cnt, const int* __restrict__ boff,
                        int* __restrict__ off, int* __restrict__ cur) {
  const int i = blockIdx.x * 256 + threadIdx.x;
  const int v = (i < NN) ? cnt[i] : 0;
  int tot;
  const int excl = block_scan_excl_256(v, &tot) + boff[blockIdx.x];
  if (i < NN) {
    off[i] = excl;
    cur[i] = excl;
  }
  if (i == NN) off[NN] = excl;
}

__global__ void k_edge2(const int* __restrict__ src, const int* __restrict__ dst,
                        const float* __restrict__ w, const float* __restrict__ dinv,
                        int* __restrict__ cur, int2* __restrict__ ed) {
  const int e = blockIdx.x * blockDim.x + threadIdx.x;
  if (e >= EE) return;
  const int s = src[e], d = dst[e];
  const int p = atomicAdd(&cur[d], 1);
  int2 rec;
  rec.x = s;
  rec.y = __float_as_int(-w[e] * dinv[s] * dinv[d]);
  ed[p] = rec;
}

// ---------------- sparse gather (bf16 rows, 1 wave per node) ----------------
__global__ __launch_bounds__(256) void k_gather(
    const char* __restrict__ vinB, const char* __restrict__ vsubB, const float alpha,
    const int* __restrict__ off, const int2* __restrict__ ed, char* __restrict__ voutB) {
  const int wid = threadIdx.x >> 6, lane = threadIdx.x & 63;
  const int node = blockIdx.x * 4 + wid;
  const int p0 = off[node], p1 = off[node + 1];
  const int lb = lane * 4;
  float ax0 = 0.f, ay0 = 0.f, ax1 = 0.f, ay1 = 0.f;
  float ax2 = 0.f, ay2 = 0.f, ax3 = 0.f, ay3 = 0.f;
  int p = p0;
  for (; p + 3 < p1; p += 4) {
    const int2 e0 = ed[p], e1 = ed[p + 1], e2 = ed[p + 2], e3 = ed[p + 3];
    const unsigned v0 = *(const unsigned*)(vinB + e0.x * 512 + lb);
    const unsigned v1 = *(const unsigned*)(vinB + e1.x * 512 + lb);
    const unsigned v2 = *(const unsigned*)(vinB + e2.x * 512 + lb);
    const unsigned v3 = *(const unsigned*)(vinB + e3.x * 512 + lb);
    const float w0 = __int_as_float(e0.y), w1 = __int_as_float(e1.y);
    const float w2 = __int_as_float(e2.y), w3 = __int_as_float(e3.y);
    ax0 = fmaf(w0, bf2f((unsigned short)v0), ax0);
    ay0 = fmaf(w0, bf2f((unsigned short)(v0 >> 16)), ay0);
    ax1 = fmaf(w1, bf2f((unsigned short)v1), ax1);
    ay1 = fmaf(w1, bf2f((unsigned short)(v1 >> 16)), ay1);
    ax2 = fmaf(w2, bf2f((unsigned short)v2), ax2);
    ay2 = fmaf(w2, bf2f((unsigned short)(v2 >> 16)), ay2);
    ax3 = fmaf(w3, bf2f((unsigned short)v3), ax3);
    ay3 = fmaf(w3, bf2f((unsigned short)(v3 >> 16)), ay3);
  }
  for (; p < p1; ++p) {
    const int2 e0 = ed[p];
    const unsigned v0 = *(const unsigned*)(vinB + e0.x * 512 + lb);
    const float w0 = __int_as_float(e0.y);
    ax0 = fmaf(w0, bf2f((unsigned short)v0), ax0);
    ay0 = fmaf(w0, bf2f((unsigned short)(v0 >> 16)), ay0);
  }
  float rx = alpha * ((ax0 + ax1) + (ax2 + ax3));
  float ry = alpha * ((ay0 + ay1) + (ay2 + ay3));
  if (vsubB) {
    const unsigned s = *(const unsigned*)(vsubB + node * 512 + lb);
    rx -= bf2f((unsigned short)s);
    ry -= bf2f((unsigned short)(s >> 16));
  }
  const unsigned ow = (unsigned)f2bf(rx) | ((unsigned)f2bf(ry) << 16);
  *(unsigned*)(voutB + node * 512 + lb) = ow;
}

// ---------------- dense stage ----------------
// A = [xb | hb | tx1b | tx2b] (N x 512 bf16, packed in d_out rows), B fragment-
// native in bglob. Block = 64 rows x 512 cols, 4 waves (wave w: all 64 rows x
// cols cf [w*8, w*8+8)). A tile (4KB/k-step) staged ONCE per block to LDS as
// fragments via global_load_lds with fragment-permuted source addresses
// (dest lane-linear). B k-frags register-loaded from L2 (ping-pong). One
// __syncthreads per k-step; stage(ks+1)+loadB(ks+1) issued before MFMA(ks).
__global__ __launch_bounds__(256, 2) void k_gemm(
    const char* __restrict__ outB, const unsigned short* __restrict__ bglob,
    const float* __restrict__ c_prev,
    const float* __restrict__ b_i, const float* __restrict__ b_f,
    const float* __restrict__ b_c, const float* __restrict__ b_o,
    const float* __restrict__ w_ci, const float* __restrict__ w_cf,
    const float* __restrict__ w_co, float* __restrict__ h_out,
    float* __restrict__ c_out) {
  __shared__ char lds[2][4096];
  const int tid = threadIdx.x;
  const int lane = tid & 63;
  const int wid = tid >> 6;
  const int kg = lane >> 4;
  const int lm = lane & 15;
  const int m0 = blockIdx.x * 64;

  const char* hB = outB;                   // +0: tx1b, +256: hb
  const char* cB = outB + (long)NN * 512;  // +0: tx2b, +256: xb

  // staging address for this thread: frag rf=wid, frag-lane = tid&63
  const int srow0 = m0 + wid * 16 + lm;
  const long srow = (srow0 < NN) ? srow0 : (NN - 1);
  const int schunk = kg * 16;  // k-chunk within the row's 64B slice

  f32x4 acc[32];  // acc[rf*8 + i], i = hl*4+g
#pragma unroll
  for (int i = 0; i < 32; ++i) acc[i] = (f32x4){0.f, 0.f, 0.f, 0.f};

  auto stage = [&](int ks, int buf) {
    const char* base = (ks < 4) ? (cB + 256) : (ks < 8) ? (hB + 256) : (ks < 12) ? hB : cB;
    async_copy16(base + srow * 512 + (ks & 3) * 64 + schunk, &lds[buf][tid * 16]);
  };

  bf16x8 br0[8], br1[8];
  auto loadB = [&](int ks, bf16x8* bb) {
    const unsigned short* fp = bglob + ((ks * 32 + wid * 8) * 64 + lane) * 8;
#pragma unroll
    for (int i = 0; i < 8; ++i) bb[i] = *(const bf16x8*)(fp + i * 512);
  };

  stage(0, 0);
  loadB(0, br0);
  __syncthreads();

#pragma unroll
  for (int ks = 0; ks < 16; ++ks) {
    const int buf = ks & 1;
    if (ks < 15) {
      stage(ks + 1, buf ^ 1);
      loadB(ks + 1, (ks & 1) ? br0 : br1);
    }
    bf16x8 a[4];
#pragma unroll
    for (int rf = 0; rf < 4; ++rf)
      a[rf] = *(const bf16x8*)(&lds[buf][rf * 1024 + lane * 16]);
    const bf16x8* br = (ks & 1) ? br1 : br0;
#pragma unroll
    for (int rf = 0; rf < 4; ++rf)
#pragma unroll
      for (int i = 0; i < 8; ++i)
        acc[rf * 8 + i] =
            __builtin_amdgcn_mfma_f32_16x16x32_bf16(a[rf], br[i], acc[rf * 8 + i], 0, 0, 0);
    __syncthreads();
  }

  // Epilogue: node = m0+rf*16+kg*4+reg, hc = (2*wid+hl)*16+lm
#pragma unroll
  for (int hl = 0; hl < 2; ++hl) {
    const int hc = (wid * 2 + hl) * 16 + lm;
    const float bi = b_i[hc], bfv = b_f[hc], bc = b_c[hc], bo = b_o[hc];
    const float wci = w_ci[hc], wcf = w_cf[hc], wco = w_co[hc];
#pragma unroll
    for (int rf = 0; rf < 4; ++rf) {
#pragma unroll
      for (int reg = 0; reg < 4; ++reg) {
        const int node = m0 + rf * 16 + kg * 4 + reg;
        if (node < NN) {
          const float cp = c_prev[node * 128 + hc];
          const float pi = acc[rf * 8 + hl * 4 + 0][reg] + bi + wci * cp;
          const float pf = acc[rf * 8 + hl * 4 + 1][reg] + bfv + wcf * cp;
          const float pc = acc[rf * 8 + hl * 4 + 2][reg] + bc;
          const float po = acc[rf * 8 + hl * 4 + 3][reg] + bo;
          const float ig = 1.f / (1.f + __expf(-pi));
          const float fg = 1.f / (1.f + __expf(-pf));
          const float ct = fg * cp + ig * tanhf(pc);
          const float og = 1.f / (1.f + __expf(-(po + wco * ct)));
          h_out[node * 128 + hc] = og * tanhf(ct);
          c_out[node * 128 + hc] = ct;
        }
      }
    }
  }
}

// ---------------- launcher ----------------

extern "C" void kernel_launch(void* const* d_in, const int* in_sizes, int n_in,
                              void* d_out, int out_size, void* d_ws, size_t ws_size,
                              hipStream_t stream) {
  const float* x_t    = (const float*)d_in[0];
  const float* h_prev = (const float*)d_in[1];
  const float* c_prev = (const float*)d_in[2];
  const float* ew     = (const float*)d_in[3];
  const int*   eidx   = (const int*)d_in[4];
  const float* Wi = (const float*)d_in[5];
  const float* Wf = (const float*)d_in[6];
  const float* Wc = (const float*)d_in[7];
  const float* Wo = (const float*)d_in[8];
  const float* Ti = (const float*)d_in[9];
  const float* Tf = (const float*)d_in[10];
  const float* Tc = (const float*)d_in[11];
  const float* To = (const float*)d_in[12];
  const float* bi = (const float*)d_in[13];
  const float* bf = (const float*)d_in[14];
  const float* bc = (const float*)d_in[15];
  const float* bo = (const float*)d_in[16];
  const float* wci = (const float*)d_in[17];
  const float* wcf = (const float*)d_in[18];
  const float* wco = (const float*)d_in[19];

  char* ws = (char*)d_ws;
  float* deg  = (float*)(ws + 0);        // 200192
  int*   cnt  = (int*)(ws + 200192);     // 200192
  float* dinv = (float*)(ws + 400384);   // 200192
  int*   off  = (int*)(ws + 600576);     // 200704
  int*   cur  = (int*)(ws + 801280);     // 200704
  int*   bsum = (int*)(ws + 1001984);    // 1024
  int*   boff = (int*)(ws + 1003008);    // 1024
  int2*  ed   = (int2*)(ws + 1004032);   // 6400000
  unsigned short* bglob = (unsigned short*)(ws + 7404032);  // 524288

  char* outB = (char*)d_out;  // h-rows: [tx1b|hb]; c-rows: [tx2b|xb]
  float* h_out = (float*)d_out;
  float* c_out = h_out + (long)NN * 128;

  const int* esrc = eidx;
  const int* edst = eidx + EE;

  hipMemsetAsync(ws, 0, 400384, stream);  // deg + cnt

  k_pre<<<9503, 256, 0, stream>>>(Wi, Wf, Wc, Wo, Ti, Tf, Tc, To, bglob,
                                  h_prev, x_t, outB, esrc, edst, ew, deg, cnt);
  k_phase2<<<392, 256, 0, stream>>>(deg, dinv, cnt, bsum);
  k_scan2<<<1, 256, 0, stream>>>(bsum, boff, 196);
  k_scan3<<<196, 256, 0, stream>>>(cnt, boff, off, cur);
  k_edge2<<<3125, 256, 0, stream>>>(esrc, edst, ew, dinv, cur, ed);
  k_gather<<<12500, 256, 0, stream>>>(outB + 256, nullptr, 1.f, off, ed, outB);
  k_gather<<<12500, 256, 0, stream>>>(outB, outB + 256, 2.f, off, ed,
                                      outB + (long)NN * 512);
  k_gemm<<<782, 256, 0, stream>>>(outB, bglob, c_prev,
                                  bi, bf, bc, bo, wci, wcf, wco, h_out, c_out);
}